// Round 1
// baseline (7251.015 us; speedup 1.0000x reference)
//
#include <hip/hip_runtime.h>

typedef _Float16 half8 __attribute__((ext_vector_type(8)));
typedef float f32x4 __attribute__((ext_vector_type(4)));

#define BB 64
#define SS 512
#define DD 512
#define HH 1024
#define KK 1536            // D + H
#define NBLK 64            // H / 16
#define AELEMS (BB * KK)   // one activation buffer, elements

// permute k within each 32-block so one contiguous 16B lane-load yields the
// mfma_16x16x32 fragment order: elems[0..3]=k(kg*4+j), elems[4..7]=k(16+kg*4+j)
__device__ __host__ __forceinline__ int kperm(int k) {
  int blk = k >> 5, r = k & 31;
  return (blk << 5) | (((r >> 2) & 3) << 3) | ((r >> 4) << 2) | (r & 3);
}

// Pack weights: Wp[p][k'] fp16, p = b*80 + tile*16 + c  (tile: 0=g,1=r,2=z,3=i_n,4=h_n)
// rows k<512 from x-side weights, k>=512 from h-side; zero-padded where dead.
__global__ void prep_w(const float* __restrict__ Wg, const float* __restrict__ Wih,
                       const float* __restrict__ Whh, _Float16* __restrict__ Wp) {
  int p = blockIdx.x;                       // 0..5119
  int b = p / 80, rem = p % 80, t = rem >> 4, c = rem & 15;
  int j = b * 16 + c;                       // h-column 0..1023
  for (int pass = 0; pass < 6; ++pass) {
    int k = pass * 256 + threadIdx.x;       // 0..1535
    float v;
    if (t == 0)      v = Wg[k * HH + j];
    else if (t == 1) v = (k < DD) ? Wih[k * 3 * HH + j]          : Whh[(k - DD) * 3 * HH + j];
    else if (t == 2) v = (k < DD) ? Wih[k * 3 * HH + HH + j]     : Whh[(k - DD) * 3 * HH + HH + j];
    else if (t == 3) v = (k < DD) ? Wih[k * 3 * HH + 2 * HH + j] : 0.f;
    else             v = (k < DD) ? 0.f : Whh[(k - DD) * 3 * HH + 2 * HH + j];
    Wp[(size_t)p * KK + kperm(k)] = (_Float16)v;
  }
}

// A0 = [fp16(x[:,0,:]) | h0=0], k-permuted
__global__ void init_a(const float* __restrict__ x, _Float16* __restrict__ A0) {
  int b = blockIdx.x, tid = threadIdx.x;
  for (int d = tid; d < DD; d += 256)
    A0[b * KK + kperm(d)] = (_Float16)x[((size_t)b * SS) * DD + d];
  for (int k = DD + tid; k < KK; k += 256)
    A0[b * KK + kperm(k)] = (_Float16)0.f;
}

__global__ __launch_bounds__(512) void rnn_seq(
    const float* __restrict__ x, const _Float16* __restrict__ Wp,
    const float* __restrict__ bg, const float* __restrict__ bih,
    const float* __restrict__ bhh, float* __restrict__ out,
    _Float16* __restrict__ Abuf, unsigned* __restrict__ bar) {
  const int blk = blockIdx.x;          // column block 0..63
  const int tid = threadIdx.x;
  const int w = tid >> 6;              // wave 0..7 (K-split)
  const int lane = tid & 63;
  const int lrow = lane & 15;          // fragment row (A) / col (B)
  const int lkg = lane >> 4;           // fragment k-group

  __shared__ float Red[4][80][65];     // [wavepair][slab col][row(+pad)] 83.2 KB -> 1 block/CU

  // epilogue mapping: thread -> (rows 2*erp, 2*erp+1) x col ej
  const int ej = tid & 15;
  const int erp = tid >> 4;            // 0..31
  const int r0 = erp * 2;
  const int ghcol = blk * 16 + ej;
  const float bg_b  = bg[ghcol];
  const float br_b  = bih[ghcol] + bhh[ghcol];
  const float bz_b  = bih[HH + ghcol] + bhh[HH + ghcol];
  const float bin_b = bih[2 * HH + ghcol];
  const float bhn_b = bhh[2 * HH + ghcol];
  const int hpos = kperm(DD + ghcol);
  float hreg0 = 0.f, hreg1 = 0.f;

  // resident weights: tiles 0..2 (full K), this wave's 6 k-steps. 72 VGPRs.
  half8 bfrag[3][6];
#pragma unroll
  for (int tt = 0; tt < 3; ++tt)
#pragma unroll
    for (int kk = 0; kk < 6; ++kk) {
      int wk = w * 6 + kk;
      bfrag[tt][kk] = *(const half8*)(Wp + (size_t)(blk * 80 + tt * 16 + lrow) * KK + wk * 32 + lkg * 8);
    }

  unsigned gen = 0;
  for (int t = 0; t < SS; ++t) {
    const _Float16* A = Abuf + (t & 1) * AELEMS;
    _Float16* An = Abuf + ((t + 1) & 1) * AELEMS;

    f32x4 zz = {0.f, 0.f, 0.f, 0.f};
    f32x4 acc[5][4];
#pragma unroll
    for (int tt = 0; tt < 5; ++tt)
#pragma unroll
      for (int mt = 0; mt < 4; ++mt) acc[tt][mt] = zz;

#pragma unroll
    for (int kk = 0; kk < 6; ++kk) {
      const int wk = w * 6 + kk;
      half8 afr[4];
#pragma unroll
      for (int mt = 0; mt < 4; ++mt)
        afr[mt] = *(const half8*)(A + (mt * 16 + lrow) * KK + wk * 32 + lkg * 8);
#pragma unroll
      for (int tt = 0; tt < 3; ++tt)
#pragma unroll
        for (int mt = 0; mt < 4; ++mt)
          acc[tt][mt] = __builtin_amdgcn_mfma_f32_16x16x32_f16(afr[mt], bfrag[tt][kk], acc[tt][mt], 0, 0, 0);
      if (wk < 16) {  // tile 3 (i_n): live rows k<512 only
        half8 b3 = *(const half8*)(Wp + (size_t)(blk * 80 + 48 + lrow) * KK + wk * 32 + lkg * 8);
#pragma unroll
        for (int mt = 0; mt < 4; ++mt)
          acc[3][mt] = __builtin_amdgcn_mfma_f32_16x16x32_f16(afr[mt], b3, acc[3][mt], 0, 0, 0);
      } else {        // tile 4 (h_n): live rows k>=512 only
        half8 b4 = *(const half8*)(Wp + (size_t)(blk * 80 + 64 + lrow) * KK + wk * 32 + lkg * 8);
#pragma unroll
        for (int mt = 0; mt < 4; ++mt)
          acc[4][mt] = __builtin_amdgcn_mfma_f32_16x16x32_f16(afr[mt], b4, acc[4][mt], 0, 0, 0);
      }
    }

    // cross-wave reduction (8 partials -> 4 slabs -> summed in epilogue)
    __syncthreads();
    if (w < 4) {
#pragma unroll
      for (int tt = 0; tt < 5; ++tt)
#pragma unroll
        for (int mt = 0; mt < 4; ++mt)
#pragma unroll
          for (int r = 0; r < 4; ++r)
            Red[w][tt * 16 + lrow][mt * 16 + lkg * 4 + r] = acc[tt][mt][r];
    }
    __syncthreads();
    if (w >= 4) {
#pragma unroll
      for (int tt = 0; tt < 5; ++tt)
#pragma unroll
        for (int mt = 0; mt < 4; ++mt)
#pragma unroll
          for (int r = 0; r < 4; ++r)
            Red[w - 4][tt * 16 + lrow][mt * 16 + lkg * 4 + r] += acc[tt][mt][r];
    }
    __syncthreads();

    // epilogue: 2 outputs per thread (rows r0, r0+1; column ghcol)
    float s0[5], s1[5];
#pragma unroll
    for (int g = 0; g < 5; ++g) {
      float a0 = 0.f, a1 = 0.f;
#pragma unroll
      for (int ww = 0; ww < 4; ++ww) {
        a0 += Red[ww][g * 16 + ej][r0];
        a1 += Red[ww][g * 16 + ej][r0 + 1];
      }
      s0[g] = a0; s1[g] = a1;
    }
#pragma unroll
    for (int rr = 0; rr < 2; ++rr) {
      const float* s = rr ? s1 : s0;
      float hprev = rr ? hreg1 : hreg0;
      float g_ = 1.f / (1.f + __expf(-(s[0] + bg_b)));
      float r_ = 1.f / (1.f + __expf(-(s[1] + br_b)));
      float z_ = 1.f / (1.f + __expf(-(s[2] + bz_b)));
      float n_ = tanhf(s[3] + bin_b + r_ * (s[4] + bhn_b));
      float h = g_ * ((1.f - z_) * n_ + z_ * hprev);
      if (rr) hreg1 = h; else hreg0 = h;
      if (t == SS - 1) out[(r0 + rr) * HH + ghcol] = h;
      else             An[(r0 + rr) * KK + hpos] = (_Float16)h;
    }
    if (t < SS - 1)   // x part for step t+1: thread tid handles d = tid
      An[blk * KK + kperm(tid)] = (_Float16)x[((size_t)blk * SS + t + 1) * DD + tid];

    // grid barrier (device-scope; publishes An, invalidates stale L2)
    __syncthreads();
    if (tid == 0) {
      unsigned old = __hip_atomic_fetch_add(bar, 1u, __ATOMIC_ACQ_REL, __HIP_MEMORY_SCOPE_AGENT);
      if (old == NBLK - 1) {
        __hip_atomic_store(bar, 0u, __ATOMIC_RELAXED, __HIP_MEMORY_SCOPE_AGENT);
        __hip_atomic_store(bar + 32, gen + 1, __ATOMIC_RELEASE, __HIP_MEMORY_SCOPE_AGENT);
      } else {
        while (__hip_atomic_load(bar + 32, __ATOMIC_ACQUIRE, __HIP_MEMORY_SCOPE_AGENT) <= gen)
          __builtin_amdgcn_s_sleep(2);
      }
    }
    gen++;
    __syncthreads();
  }
}

extern "C" void kernel_launch(void* const* d_in, const int* in_sizes, int n_in,
                              void* d_out, int out_size, void* d_ws, size_t ws_size,
                              hipStream_t stream) {
  const float* x   = (const float*)d_in[0];
  const float* Wg  = (const float*)d_in[1];
  const float* bg  = (const float*)d_in[2];
  const float* Wih = (const float*)d_in[3];
  const float* bih = (const float*)d_in[4];
  const float* Whh = (const float*)d_in[5];
  const float* bhh = (const float*)d_in[6];
  // d_in[7..10] (Wa, ba, Ws, bs) are mathematically dead: softmax over size-1 axis == 1
  float* out = (float*)d_out;

  char* ws = (char*)d_ws;
  _Float16* Wp   = (_Float16*)ws;                       // 5120*1536*2 = 15,728,640 B
  _Float16* Abuf = (_Float16*)(ws + 15728640);          // 2*64*1536*2 =   393,216 B
  unsigned* bar  = (unsigned*)(ws + 15728640 + 393216); //                     256 B

  hipMemsetAsync(bar, 0, 256, stream);
  prep_w<<<5120, 256, 0, stream>>>(Wg, Wih, Whh, Wp);
  init_a<<<64, 256, 0, stream>>>(x, Abuf);
  rnn_seq<<<64, 512, 0, stream>>>(x, Wp, bg, bih, bhh, out, Abuf, bar);
}

// Round 2
// 6635.908 us; speedup vs baseline: 1.0927x; 1.0927x over previous
//
#include <hip/hip_runtime.h>

typedef _Float16 half8 __attribute__((ext_vector_type(8)));
typedef float f32x4 __attribute__((ext_vector_type(4)));

#define BB 64
#define SS 512
#define DD 512
#define HH 1024
#define KK 1536            // D + H
#define NBLK 64            // H / 16
#define AELEMS (BB * KK)   // one activation buffer, elements

// permute k within each 32-block so one contiguous 16B lane-load yields the
// mfma_16x16x32 fragment order: elems[0..3]=k(kg*4+j), elems[4..7]=k(16+kg*4+j)
__device__ __host__ __forceinline__ int kperm(int k) {
  int blk = k >> 5, r = k & 31;
  return (blk << 5) | (((r >> 2) & 3) << 3) | ((r >> 4) << 2) | (r & 3);
}

// Pack weights: Wp[p][k'] fp16, p = b*80 + tile*16 + c  (tile: 0=g,1=r,2=z,3=i_n,4=h_n)
__global__ void prep_w(const float* __restrict__ Wg, const float* __restrict__ Wih,
                       const float* __restrict__ Whh, _Float16* __restrict__ Wp) {
  int p = blockIdx.x;                       // 0..5119
  int b = p / 80, rem = p % 80, t = rem >> 4, c = rem & 15;
  int j = b * 16 + c;                       // h-column 0..1023
  for (int pass = 0; pass < 6; ++pass) {
    int k = pass * 256 + threadIdx.x;       // 0..1535
    float v;
    if (t == 0)      v = Wg[k * HH + j];
    else if (t == 1) v = (k < DD) ? Wih[k * 3 * HH + j]          : Whh[(k - DD) * 3 * HH + j];
    else if (t == 2) v = (k < DD) ? Wih[k * 3 * HH + HH + j]     : Whh[(k - DD) * 3 * HH + HH + j];
    else if (t == 3) v = (k < DD) ? Wih[k * 3 * HH + 2 * HH + j] : 0.f;
    else             v = (k < DD) ? 0.f : Whh[(k - DD) * 3 * HH + 2 * HH + j];
    Wp[(size_t)p * KK + kperm(k)] = (_Float16)v;
  }
}

// A0 = [fp16(x[:,0,:]) | h0=0], k-permuted
__global__ void init_a(const float* __restrict__ x, _Float16* __restrict__ A0) {
  int b = blockIdx.x, tid = threadIdx.x;
  for (int d = tid; d < DD; d += 256)
    A0[b * KK + kperm(d)] = (_Float16)x[((size_t)b * SS) * DD + d];
  for (int k = DD + tid; k < KK; k += 256)
    A0[b * KK + kperm(k)] = (_Float16)0.f;
}

__global__ __launch_bounds__(512, 2) void rnn_seq(
    const float* __restrict__ x, const _Float16* __restrict__ Wp,
    const float* __restrict__ bg, const float* __restrict__ bih,
    const float* __restrict__ bhh, float* __restrict__ out,
    _Float16* __restrict__ Abuf, unsigned* __restrict__ flags) {
  const int blk = blockIdx.x;          // column block 0..63
  const int tid = threadIdx.x;
  const int w = tid >> 6;              // wave 0..7 (K-split)
  const int lane = tid & 63;
  const int lrow = lane & 15;          // fragment row (A) / col (B)
  const int lkg = lane >> 4;           // fragment k-group

  // [partial 0..3][slab col 0..79][row 0..63 (+4 pad)] — stride 68 words:
  // start bank = 4*(col+kgroup) mod 32 -> exactly 8 words/bank (minimal)
  __shared__ float Red[4][80][68];     // 87,040 B -> 1 block/CU

  // epilogue mapping (threads 0..255): col ej, rows rq*4 .. rq*4+3
  const int ej = tid & 15;
  const int rq = (tid >> 4) & 15;
  const int ghcol = blk * 16 + ej;
  const float bg_b  = bg[ghcol];
  const float br_b  = bih[ghcol] + bhh[ghcol];
  const float bz_b  = bih[HH + ghcol] + bhh[HH + ghcol];
  const float bin_b = bih[2 * HH + ghcol];
  const float bhn_b = bhh[2 * HH + ghcol];
  const int hpos = kperm(DD + ghcol);
  float hreg[4] = {0.f, 0.f, 0.f, 0.f};

  // ALL weights register-resident: 3 full-K tiles (72 VGPR) + the live half
  // of tiles 3/4 (24 VGPR). Survives per-step L2 invalidation for free.
  half8 bfrag[3][6];
  half8 bext[6];
#pragma unroll
  for (int tt = 0; tt < 3; ++tt)
#pragma unroll
    for (int kk = 0; kk < 6; ++kk) {
      int wk = w * 6 + kk;
      bfrag[tt][kk] = *(const half8*)(Wp + (size_t)(blk * 80 + tt * 16 + lrow) * KK + wk * 32 + lkg * 8);
    }
#pragma unroll
  for (int kk = 0; kk < 6; ++kk) {
    int wk = w * 6 + kk;
    int trow = (wk < 16) ? 48 : 64;    // tile 3 (i_n, k<512) else tile 4 (h_n)
    bext[kk] = *(const half8*)(Wp + (size_t)(blk * 80 + trow + lrow) * KK + wk * 32 + lkg * 8);
  }

  for (int t = 0; t < SS; ++t) {
    const _Float16* A = Abuf + (t & 1) * AELEMS;
    _Float16* An = Abuf + ((t + 1) & 1) * AELEMS;

    // x(t+1) -> An, issued at the top of the step: An's previous contents are
    // dead (all blocks passed barrier t-1), and the HBM latency hides under
    // the MFMA loop. Published later by this block's flag release.
    if (t < SS - 1)
      An[blk * KK + kperm(tid)] = (_Float16)x[((size_t)blk * SS + t + 1) * DD + tid];

    f32x4 zz = {0.f, 0.f, 0.f, 0.f};
    f32x4 acc[5][4];
#pragma unroll
    for (int tt = 0; tt < 5; ++tt)
#pragma unroll
      for (int mt = 0; mt < 4; ++mt) acc[tt][mt] = zz;

#pragma unroll
    for (int kk = 0; kk < 6; ++kk) {
      const int wk = w * 6 + kk;
      half8 afr[4];
#pragma unroll
      for (int mt = 0; mt < 4; ++mt)
        afr[mt] = *(const half8*)(A + (mt * 16 + lrow) * KK + wk * 32 + lkg * 8);
#pragma unroll
      for (int tt = 0; tt < 3; ++tt)
#pragma unroll
        for (int mt = 0; mt < 4; ++mt)
          acc[tt][mt] = __builtin_amdgcn_mfma_f32_16x16x32_f16(afr[mt], bfrag[tt][kk], acc[tt][mt], 0, 0, 0);
      const int et = (wk < 16) ? 3 : 4;
#pragma unroll
      for (int mt = 0; mt < 4; ++mt)
        acc[et][mt] = __builtin_amdgcn_mfma_f32_16x16x32_f16(afr[mt], bext[kk], acc[et][mt], 0, 0, 0);
    }

    // ---- vectorized 2-phase cross-wave reduction (8 partials -> 4) ----
    __syncthreads();
    if (w >= 4) {
#pragma unroll
      for (int tt = 0; tt < 5; ++tt)
#pragma unroll
        for (int mt = 0; mt < 4; ++mt)
          *(f32x4*)&Red[w - 4][tt * 16 + lrow][mt * 16 + lkg * 4] = acc[tt][mt];
    }
    __syncthreads();
    if (w < 4) {
#pragma unroll
      for (int tt = 0; tt < 5; ++tt)
#pragma unroll
        for (int mt = 0; mt < 4; ++mt) {
          f32x4* p = (f32x4*)&Red[w][tt * 16 + lrow][mt * 16 + lkg * 4];
          *p = *p + acc[tt][mt];
        }
    }
    __syncthreads();

    // ---- epilogue: 256 threads, 4 rows x 1 col each, f32x4 reads ----
    if (tid < 256) {
      f32x4 s[5];
#pragma unroll
      for (int g = 0; g < 5; ++g) {
        f32x4 a = *(const f32x4*)&Red[0][g * 16 + ej][rq * 4];
#pragma unroll
        for (int ww = 1; ww < 4; ++ww)
          a = a + *(const f32x4*)&Red[ww][g * 16 + ej][rq * 4];
        s[g] = a;
      }
#pragma unroll
      for (int r = 0; r < 4; ++r) {
        float g_ = 1.f / (1.f + __expf(-(s[0][r] + bg_b)));
        float r_ = 1.f / (1.f + __expf(-(s[1][r] + br_b)));
        float z_ = 1.f / (1.f + __expf(-(s[2][r] + bz_b)));
        float n_ = tanhf(s[3][r] + bin_b + r_ * (s[4][r] + bhn_b));
        float h = g_ * ((1.f - z_) * n_ + z_ * hreg[r]);
        hreg[r] = h;
        int row = rq * 4 + r;
        if (t == SS - 1) out[row * HH + ghcol] = h;
        else             An[row * KK + hpos] = (_Float16)h;
      }
    }

    if (t < SS - 1) {
      __syncthreads();                 // all An writes done
      // flag barrier: own-flag release, 64-lane parallel acquire poll
      if (tid == 0)
        __hip_atomic_store(&flags[blk], (unsigned)(t + 1), __ATOMIC_RELEASE, __HIP_MEMORY_SCOPE_AGENT);
      if (tid < 64) {
        for (;;) {
          unsigned v = __hip_atomic_load(&flags[tid], __ATOMIC_ACQUIRE, __HIP_MEMORY_SCOPE_AGENT);
          if (__all((int)(v > (unsigned)t))) break;
          __builtin_amdgcn_s_sleep(1);
        }
      }
      __syncthreads();
    }
  }
}

extern "C" void kernel_launch(void* const* d_in, const int* in_sizes, int n_in,
                              void* d_out, int out_size, void* d_ws, size_t ws_size,
                              hipStream_t stream) {
  const float* x   = (const float*)d_in[0];
  const float* Wg  = (const float*)d_in[1];
  const float* bg  = (const float*)d_in[2];
  const float* Wih = (const float*)d_in[3];
  const float* bih = (const float*)d_in[4];
  const float* Whh = (const float*)d_in[5];
  const float* bhh = (const float*)d_in[6];
  // d_in[7..10] (Wa, ba, Ws, bs) are mathematically dead: softmax over size-1 axis == 1
  float* out = (float*)d_out;

  char* ws = (char*)d_ws;
  _Float16* Wp    = (_Float16*)ws;                       // 5120*1536*2 = 15,728,640 B
  _Float16* Abuf  = (_Float16*)(ws + 15728640);          // 2*64*1536*2 =   393,216 B
  unsigned* flags = (unsigned*)(ws + 15728640 + 393216); // 64*4 = 256 B

  hipMemsetAsync(flags, 0, 256, stream);
  prep_w<<<5120, 256, 0, stream>>>(Wg, Wih, Whh, Wp);
  init_a<<<64, 256, 0, stream>>>(x, Abuf);
  rnn_seq<<<64, 512, 0, stream>>>(x, Wp, bg, bih, bhh, out, Abuf, flags);
}

// Round 3
// 5962.367 us; speedup vs baseline: 1.2161x; 1.1130x over previous
//
#include <hip/hip_runtime.h>

typedef _Float16 half8 __attribute__((ext_vector_type(8)));
typedef float f32x4 __attribute__((ext_vector_type(4)));
typedef float f32x2 __attribute__((ext_vector_type(2)));

#define BB 64
#define SS 512
#define DD 512
#define HH 1024
#define KK 1536            // D + H
#define NBLK 64            // H / 16

// permute k within each 32-block so one contiguous 16B lane-load yields the
// mfma_16x16x32 fragment order: elems[0..3]=k(kg*4+j), elems[4..7]=k(16+kg*4+j)
__device__ __host__ __forceinline__ int kperm(int k) {
  int blk = k >> 5, r = k & 31;
  return (blk << 5) | (((r >> 2) & 3) << 3) | ((r >> 4) << 2) | (r & 3);
}

// Pack weights: Wp[p][k'] fp16, p = b*80 + tile*16 + c  (tile: 0=g,1=r,2=z,3=i_n,4=h_n)
__global__ void prep_w(const float* __restrict__ Wg, const float* __restrict__ Wih,
                       const float* __restrict__ Whh, _Float16* __restrict__ Wp) {
  int p = blockIdx.x;                       // 0..5119
  int b = p / 80, rem = p % 80, t = rem >> 4, c = rem & 15;
  int j = b * 16 + c;                       // h-column 0..1023
  for (int pass = 0; pass < 6; ++pass) {
    int k = pass * 256 + threadIdx.x;       // 0..1535
    float v;
    if (t == 0)      v = Wg[k * HH + j];
    else if (t == 1) v = (k < DD) ? Wih[k * 3 * HH + j]          : Whh[(k - DD) * 3 * HH + j];
    else if (t == 2) v = (k < DD) ? Wih[k * 3 * HH + HH + j]     : Whh[(k - DD) * 3 * HH + HH + j];
    else if (t == 3) v = (k < DD) ? Wih[k * 3 * HH + 2 * HH + j] : 0.f;
    else             v = (k < DD) ? 0.f : Whh[(k - DD) * 3 * HH + 2 * HH + j];
    Wp[(size_t)p * KK + kperm(k)] = (_Float16)v;
  }
}

__global__ __launch_bounds__(512, 2) void rnn_seq(
    const float* __restrict__ x, const _Float16* __restrict__ Wp,
    const float* __restrict__ bg, const float* __restrict__ bih,
    const float* __restrict__ bhh, float* __restrict__ out,
    _Float16* __restrict__ Hbuf, unsigned* __restrict__ flags) {
  const int blk = blockIdx.x;          // column block 0..63
  const int tid = threadIdx.x;
  const int w = tid >> 6;              // wave 0..7
  const int lane = tid & 63;
  const int lrow = lane & 15;          // fragment row (A) / col (B)
  const int lkg = lane >> 4;           // fragment k-group

  __shared__ float Red[4][80][68];     // 87,040 B -> 1 block/CU

  // epilogue mapping (all 512 threads): col ej, rows rp*2, rp*2+1
  const int ej = tid & 15;
  const int rp = tid >> 5 == 16 ? 0 : (tid >> 4);  // placate nothing; see below
  const int rpp = tid >> 4;            // 0..31
  const int ghcol = blk * 16 + ej;
  const float bg_b  = bg[ghcol];
  const float br_b  = bih[ghcol] + bhh[ghcol];
  const float bz_b  = bih[HH + ghcol] + bhh[HH + ghcol];
  const float bin_b = bih[2 * HH + ghcol];
  const float bhn_b = bhh[2 * HH + ghcol];
  const int hposH = kperm(ghcol);      // position of our column inside Hbuf row
  float hreg[2] = {0.f, 0.f};
  (void)rp;

  // register-resident weights (24 half8 = 96 VGPR):
  // per wave: x-k range [w*64, w*64+64)  -> k-steps gx = w*2+kk   (kk=0..1)
  //           h-k range [w*128, w*128+128) in H -> k-steps gh = 16+w*4+kk (kk=0..3)
  half8 bx[3][2], b3[2], bh[3][4], b4[4];
#pragma unroll
  for (int tt = 0; tt < 3; ++tt)
#pragma unroll
    for (int kk = 0; kk < 2; ++kk)
      bx[tt][kk] = *(const half8*)(Wp + (size_t)(blk * 80 + tt * 16 + lrow) * KK + (w * 2 + kk) * 32 + lkg * 8);
#pragma unroll
  for (int kk = 0; kk < 2; ++kk)
    b3[kk] = *(const half8*)(Wp + (size_t)(blk * 80 + 48 + lrow) * KK + (w * 2 + kk) * 32 + lkg * 8);
#pragma unroll
  for (int tt = 0; tt < 3; ++tt)
#pragma unroll
    for (int kk = 0; kk < 4; ++kk)
      bh[tt][kk] = *(const half8*)(Wp + (size_t)(blk * 80 + tt * 16 + lrow) * KK + (16 + w * 4 + kk) * 32 + lkg * 8);
#pragma unroll
  for (int kk = 0; kk < 4; ++kk)
    b4[kk] = *(const half8*)(Wp + (size_t)(blk * 80 + 64 + lrow) * KK + (16 + w * 4 + kk) * 32 + lkg * 8);

  for (int t = 0; t < SS; ++t) {
    const _Float16* Hb = Hbuf + (size_t)(t & 1) * (BB * HH);
    _Float16* Hn = Hbuf + (size_t)((t + 1) & 1) * (BB * HH);

    f32x4 zz = {0.f, 0.f, 0.f, 0.f};
    f32x4 acc[5][4];
#pragma unroll
    for (int tt = 0; tt < 5; ++tt)
#pragma unroll
      for (int mt = 0; mt < 4; ++mt) acc[tt][mt] = zz;

    // ---- x-part: no cross-block dependency; direct fp32 loads from x[:,t,:].
    // Runs BEFORE the poll so inter-block skew hides behind real work.
#pragma unroll
    for (int kk = 0; kk < 2; ++kk) {
      half8 afr[4];
#pragma unroll
      for (int mt = 0; mt < 4; ++mt) {
        const float* xp = x + ((size_t)(mt * 16 + lrow) * SS + t) * DD + (w * 2 + kk) * 32 + lkg * 4;
        f32x4 f0 = *(const f32x4*)xp;
        f32x4 f1 = *(const f32x4*)(xp + 16);
        half8 hv;
#pragma unroll
        for (int j = 0; j < 4; ++j) { hv[j] = (_Float16)f0[j]; hv[4 + j] = (_Float16)f1[j]; }
        afr[mt] = hv;
      }
#pragma unroll
      for (int tt = 0; tt < 3; ++tt)
#pragma unroll
        for (int mt = 0; mt < 4; ++mt)
          acc[tt][mt] = __builtin_amdgcn_mfma_f32_16x16x32_f16(afr[mt], bx[tt][kk], acc[tt][mt], 0, 0, 0);
#pragma unroll
      for (int mt = 0; mt < 4; ++mt)
        acc[3][mt] = __builtin_amdgcn_mfma_f32_16x16x32_f16(afr[mt], b3[kk], acc[3][mt], 0, 0, 0);
    }

    // ---- wait for h(t): relaxed polls (no per-iteration fence), then one
    // acquire fence (waitcnt + buffer_inv) so cached h loads refill from LLC.
    if (tid < NBLK) {
      for (;;) {
        unsigned v = __hip_atomic_load(&flags[tid], __ATOMIC_RELAXED, __HIP_MEMORY_SCOPE_AGENT);
        if (__all((int)(v >= (unsigned)t))) break;
        __builtin_amdgcn_s_sleep(1);
      }
    }
    __syncthreads();
    __builtin_amdgcn_fence(__ATOMIC_ACQUIRE, "agent");

    // ---- h-part
#pragma unroll
    for (int kk = 0; kk < 4; ++kk) {
      const int kh = (w * 4 + kk) * 32 + lkg * 8;
      half8 afr[4];
#pragma unroll
      for (int mt = 0; mt < 4; ++mt)
        afr[mt] = *(const half8*)(Hb + (size_t)(mt * 16 + lrow) * HH + kh);
#pragma unroll
      for (int tt = 0; tt < 3; ++tt)
#pragma unroll
        for (int mt = 0; mt < 4; ++mt)
          acc[tt][mt] = __builtin_amdgcn_mfma_f32_16x16x32_f16(afr[mt], bh[tt][kk], acc[tt][mt], 0, 0, 0);
#pragma unroll
      for (int mt = 0; mt < 4; ++mt)
        acc[4][mt] = __builtin_amdgcn_mfma_f32_16x16x32_f16(afr[mt], b4[kk], acc[4][mt], 0, 0, 0);
    }

    // ---- vectorized 2-phase cross-wave reduction (8 partials -> 4) ----
    // (no barrier needed before phase 1: previous epilogue reads finished
    //  before the post-poll __syncthreads above)
    if (w >= 4) {
#pragma unroll
      for (int tt = 0; tt < 5; ++tt)
#pragma unroll
        for (int mt = 0; mt < 4; ++mt)
          *(f32x4*)&Red[w - 4][tt * 16 + lrow][mt * 16 + lkg * 4] = acc[tt][mt];
    }
    __syncthreads();
    if (w < 4) {
#pragma unroll
      for (int tt = 0; tt < 5; ++tt)
#pragma unroll
        for (int mt = 0; mt < 4; ++mt) {
          f32x4* p = (f32x4*)&Red[w][tt * 16 + lrow][mt * 16 + lkg * 4];
          *p = *p + acc[tt][mt];
        }
    }
    __syncthreads();

    // ---- epilogue: all 512 threads, 2 rows x 1 col each, f32x2 reads ----
    {
      f32x2 s[5];
#pragma unroll
      for (int g = 0; g < 5; ++g) {
        f32x2 a = *(const f32x2*)&Red[0][g * 16 + ej][rpp * 2];
#pragma unroll
        for (int ww = 1; ww < 4; ++ww)
          a = a + *(const f32x2*)&Red[ww][g * 16 + ej][rpp * 2];
        s[g] = a;
      }
#pragma unroll
      for (int r = 0; r < 2; ++r) {
        float g_ = 1.f / (1.f + __expf(-(s[0][r] + bg_b)));
        float r_ = 1.f / (1.f + __expf(-(s[1][r] + br_b)));
        float z_ = 1.f / (1.f + __expf(-(s[2][r] + bz_b)));
        float n_ = tanhf(s[3][r] + bin_b + r_ * (s[4][r] + bhn_b));
        float h = g_ * ((1.f - z_) * n_ + z_ * hreg[r]);
        hreg[r] = h;
        int row = rpp * 2 + r;
        if (t == SS - 1) {
          out[row * HH + ghcol] = h;
        } else {
          // cache-bypass store (system scope): lands at the coherent point so
          // other XCDs' post-invalidate refills see it. 2B store.
          _Float16* hp = Hn + (size_t)row * HH + hposH;
          unsigned hvb = (unsigned)__builtin_bit_cast(unsigned short, (_Float16)h);
          asm volatile("global_store_short %0, %1, off sc0 sc1" :: "v"(hp), "v"(hvb) : "memory");
        }
      }
    }

    if (t < SS - 1) {
      asm volatile("s_waitcnt vmcnt(0)" ::: "memory");  // our sc stores drained
      __syncthreads();                                  // all waves' stores drained
      if (tid == 0)                                     // publish: relaxed agent flag
        __hip_atomic_store(&flags[blk], (unsigned)(t + 1), __ATOMIC_RELAXED, __HIP_MEMORY_SCOPE_AGENT);
    }
  }
}

extern "C" void kernel_launch(void* const* d_in, const int* in_sizes, int n_in,
                              void* d_out, int out_size, void* d_ws, size_t ws_size,
                              hipStream_t stream) {
  const float* x   = (const float*)d_in[0];
  const float* Wg  = (const float*)d_in[1];
  const float* bg  = (const float*)d_in[2];
  const float* Wih = (const float*)d_in[3];
  const float* bih = (const float*)d_in[4];
  const float* Whh = (const float*)d_in[5];
  const float* bhh = (const float*)d_in[6];
  // d_in[7..10] (Wa, ba, Ws, bs) are mathematically dead: softmax over size-1 axis == 1
  float* out = (float*)d_out;

  char* ws = (char*)d_ws;
  _Float16* Wp    = (_Float16*)ws;                        // 5120*1536*2 = 15,728,640 B
  _Float16* Hbuf  = (_Float16*)(ws + 15728640);           // 2*64*1024*2 =   262,144 B
  unsigned* flags = (unsigned*)(ws + 15728640 + 262144);  // 256 B

  hipMemsetAsync((void*)Hbuf, 0, 262144 + 256, stream);   // h0 = 0, flags = 0
  prep_w<<<5120, 256, 0, stream>>>(Wg, Wih, Whh, Wp);
  rnn_seq<<<64, 512, 0, stream>>>(x, Wp, bg, bih, bhh, out, Hbuf, flags);
}

// Round 4
// 5393.249 us; speedup vs baseline: 1.3445x; 1.1055x over previous
//
#include <hip/hip_runtime.h>

typedef _Float16 half8 __attribute__((ext_vector_type(8)));
typedef float f32x4 __attribute__((ext_vector_type(4)));
typedef float f32x2 __attribute__((ext_vector_type(2)));

#define BB 64
#define SS 512
#define DD 512
#define HH 1024
#define KK 1536            // D + H
#define NBLK 64            // H / 16

// x-region only: permute k within each 32-block so one contiguous 16B lane-load
// yields the mfma_16x16x32 fragment order. h-region uses IDENTITY layout: as
// long as A and B share the same physical k order and both load contiguous
// 16B/lane, the implied permutation cancels in the MFMA dot product.
__device__ __host__ __forceinline__ int kperm(int k) {
  int blk = k >> 5, r = k & 31;
  return (blk << 5) | (((r >> 2) & 3) << 3) | ((r >> 4) << 2) | (r & 3);
}

// Pack weights: Wp[p][k'] fp16, p = b*80 + tile*16 + c  (tile: 0=g,1=r,2=z,3=i_n,4=h_n)
__global__ void prep_w(const float* __restrict__ Wg, const float* __restrict__ Wih,
                       const float* __restrict__ Whh, _Float16* __restrict__ Wp) {
  int p = blockIdx.x;                       // 0..5119
  int b = p / 80, rem = p % 80, t = rem >> 4, c = rem & 15;
  int j = b * 16 + c;                       // h-column 0..1023
  for (int pass = 0; pass < 6; ++pass) {
    int k = pass * 256 + threadIdx.x;       // 0..1535
    float v;
    if (t == 0)      v = Wg[k * HH + j];
    else if (t == 1) v = (k < DD) ? Wih[k * 3 * HH + j]          : Whh[(k - DD) * 3 * HH + j];
    else if (t == 2) v = (k < DD) ? Wih[k * 3 * HH + HH + j]     : Whh[(k - DD) * 3 * HH + HH + j];
    else if (t == 3) v = (k < DD) ? Wih[k * 3 * HH + 2 * HH + j] : 0.f;
    else             v = (k < DD) ? 0.f : Whh[(k - DD) * 3 * HH + 2 * HH + j];
    int pos = (k < DD) ? kperm(k) : k;      // x: kperm'd, h: identity
    Wp[(size_t)p * KK + pos] = (_Float16)v;
  }
}

__global__ __launch_bounds__(512, 2) void rnn_seq(
    const float* __restrict__ x, const _Float16* __restrict__ Wp,
    const float* __restrict__ bg, const float* __restrict__ bih,
    const float* __restrict__ bhh, float* __restrict__ out,
    _Float16* __restrict__ Hbuf, unsigned* __restrict__ flags) {
  const int blk = blockIdx.x;          // column block 0..63
  const int tid = threadIdx.x;
  const int w = tid >> 6;              // wave 0..7
  const int lane = tid & 63;
  const int lrow = lane & 15;          // fragment row (A) / col (B)
  const int lkg = lane >> 4;           // fragment k-group

  __shared__ float Red[4][80][68];               // 87,040 B
  __shared__ alignas(16) _Float16 Hst[64][16];   // h staging for 16B stores, 2 KB

  // epilogue mapping (all 512 threads): col ej, rows rpp*2, rpp*2+1
  const int ej = tid & 15;
  const int rpp = tid >> 4;            // 0..31
  const int ghcol = blk * 16 + ej;
  const float bg_b  = bg[ghcol];
  const float br_b  = bih[ghcol] + bhh[ghcol];
  const float bz_b  = bih[HH + ghcol] + bhh[HH + ghcol];
  const float bin_b = bih[2 * HH + ghcol];
  const float bhn_b = bhh[2 * HH + ghcol];
  float hreg[2] = {0.f, 0.f};

  // register-resident weights (24 half8 = 96 VGPR):
  // x-k: k-steps w*2+kk (kk=0..1); h-k: k-steps 16+w*4+kk (kk=0..3)
  half8 bx[3][2], b3[2], bh[3][4], b4[4];
#pragma unroll
  for (int tt = 0; tt < 3; ++tt)
#pragma unroll
    for (int kk = 0; kk < 2; ++kk)
      bx[tt][kk] = *(const half8*)(Wp + (size_t)(blk * 80 + tt * 16 + lrow) * KK + (w * 2 + kk) * 32 + lkg * 8);
#pragma unroll
  for (int kk = 0; kk < 2; ++kk)
    b3[kk] = *(const half8*)(Wp + (size_t)(blk * 80 + 48 + lrow) * KK + (w * 2 + kk) * 32 + lkg * 8);
#pragma unroll
  for (int tt = 0; tt < 3; ++tt)
#pragma unroll
    for (int kk = 0; kk < 4; ++kk)
      bh[tt][kk] = *(const half8*)(Wp + (size_t)(blk * 80 + tt * 16 + lrow) * KK + (16 + w * 4 + kk) * 32 + lkg * 8);
#pragma unroll
  for (int kk = 0; kk < 4; ++kk)
    b4[kk] = *(const half8*)(Wp + (size_t)(blk * 80 + 64 + lrow) * KK + (16 + w * 4 + kk) * 32 + lkg * 8);

  for (int t = 0; t < SS; ++t) {
    const _Float16* Hb = Hbuf + (size_t)(t & 1) * (BB * HH);
    _Float16* Hn = Hbuf + (size_t)((t + 1) & 1) * (BB * HH);

    f32x4 zz = {0.f, 0.f, 0.f, 0.f};
    f32x4 acc[5][4];
#pragma unroll
    for (int tt = 0; tt < 5; ++tt)
#pragma unroll
      for (int mt = 0; mt < 4; ++mt) acc[tt][mt] = zz;

    // ---- x-part: no cross-block dependency; overlaps other blocks' tail ----
#pragma unroll
    for (int kk = 0; kk < 2; ++kk) {
      half8 afr[4];
#pragma unroll
      for (int mt = 0; mt < 4; ++mt) {
        const float* xp = x + ((size_t)(mt * 16 + lrow) * SS + t) * DD + (w * 2 + kk) * 32 + lkg * 4;
        f32x4 f0 = *(const f32x4*)xp;
        f32x4 f1 = *(const f32x4*)(xp + 16);
        half8 hv;
#pragma unroll
        for (int j = 0; j < 4; ++j) { hv[j] = (_Float16)f0[j]; hv[4 + j] = (_Float16)f1[j]; }
        afr[mt] = hv;
      }
#pragma unroll
      for (int tt = 0; tt < 3; ++tt)
#pragma unroll
        for (int mt = 0; mt < 4; ++mt)
          acc[tt][mt] = __builtin_amdgcn_mfma_f32_16x16x32_f16(afr[mt], bx[tt][kk], acc[tt][mt], 0, 0, 0);
#pragma unroll
      for (int mt = 0; mt < 4; ++mt)
        acc[3][mt] = __builtin_amdgcn_mfma_f32_16x16x32_f16(afr[mt], b3[kk], acc[3][mt], 0, 0, 0);
    }

    // ---- wait for h(t): relaxed agent polls; no fence needed (h is read
    //      below with coherent-point sc1 loads, never through L2) ----
    if (tid < NBLK) {
      for (;;) {
        unsigned v = __hip_atomic_load(&flags[tid], __ATOMIC_RELAXED, __HIP_MEMORY_SCOPE_AGENT);
        if (__all((int)(v >= (unsigned)t))) break;
        __builtin_amdgcn_s_sleep(1);
      }
    }
    __syncthreads();
    __builtin_amdgcn_sched_barrier(0);

    // ---- h-part: sc1 loads straight from the coherent point, 2 batches ----
#pragma unroll
    for (int half = 0; half < 2; ++half) {
      half8 afr[2][4];
#pragma unroll
      for (int kk = 0; kk < 2; ++kk)
#pragma unroll
        for (int mt = 0; mt < 4; ++mt) {
          const _Float16* hp = Hb + (size_t)(mt * 16 + lrow) * HH + (w * 4 + half * 2 + kk) * 32 + lkg * 8;
          asm volatile("global_load_dwordx4 %0, %1, off sc0 sc1"
                       : "=v"(afr[kk][mt]) : "v"(hp) : "memory");
        }
      asm volatile("s_waitcnt vmcnt(0)" ::: "memory");
      __builtin_amdgcn_sched_barrier(0);
#pragma unroll
      for (int kk = 0; kk < 2; ++kk) {
#pragma unroll
        for (int tt = 0; tt < 3; ++tt)
#pragma unroll
          for (int mt = 0; mt < 4; ++mt)
            acc[tt][mt] = __builtin_amdgcn_mfma_f32_16x16x32_f16(afr[kk][mt], bh[tt][half * 2 + kk], acc[tt][mt], 0, 0, 0);
#pragma unroll
        for (int mt = 0; mt < 4; ++mt)
          acc[4][mt] = __builtin_amdgcn_mfma_f32_16x16x32_f16(afr[kk][mt], b4[half * 2 + kk], acc[4][mt], 0, 0, 0);
      }
    }

    // ---- vectorized 2-phase cross-wave reduction (8 partials -> 4) ----
    if (w >= 4) {
#pragma unroll
      for (int tt = 0; tt < 5; ++tt)
#pragma unroll
        for (int mt = 0; mt < 4; ++mt)
          *(f32x4*)&Red[w - 4][tt * 16 + lrow][mt * 16 + lkg * 4] = acc[tt][mt];
    }
    __syncthreads();
    if (w < 4) {
#pragma unroll
      for (int tt = 0; tt < 5; ++tt)
#pragma unroll
        for (int mt = 0; mt < 4; ++mt) {
          f32x4* p = (f32x4*)&Red[w][tt * 16 + lrow][mt * 16 + lkg * 4];
          *p = *p + acc[tt][mt];
        }
    }
    __syncthreads();

    // ---- epilogue: all 512 threads, 2 rows x 1 col each ----
    {
      f32x2 s[5];
#pragma unroll
      for (int g = 0; g < 5; ++g) {
        f32x2 a = *(const f32x2*)&Red[0][g * 16 + ej][rpp * 2];
#pragma unroll
        for (int ww = 1; ww < 4; ++ww)
          a = a + *(const f32x2*)&Red[ww][g * 16 + ej][rpp * 2];
        s[g] = a;
      }
#pragma unroll
      for (int r = 0; r < 2; ++r) {
        float g_ = 1.f / (1.f + __expf(-(s[0][r] + bg_b)));
        float r_ = 1.f / (1.f + __expf(-(s[1][r] + br_b)));
        float z_ = 1.f / (1.f + __expf(-(s[2][r] + bz_b)));
        float n_ = tanhf(s[3][r] + bin_b + r_ * (s[4][r] + bhn_b));
        float h = g_ * ((1.f - z_) * n_ + z_ * hreg[r]);
        hreg[r] = h;
        int row = rpp * 2 + r;
        if (t == SS - 1) out[row * HH + ghcol] = h;
        else             Hst[row][ej] = (_Float16)h;     // stage for 16B stores
      }
    }

    if (t < SS - 1) {
      __syncthreads();                 // Hst complete (also orders Red reads)
      // 128 x 16B system-scope stores: rows 0..63, two 8-col halves each.
      if (tid < 128) {
        int row = tid >> 1, hf = tid & 1;
        half8 hv = *(const half8*)&Hst[row][hf * 8];
        _Float16* hp = Hn + (size_t)row * HH + blk * 16 + hf * 8;
        asm volatile("global_store_dwordx4 %0, %1, off sc0 sc1"
                     :: "v"(hp), "v"(hv) : "memory");
      }
      asm volatile("s_waitcnt vmcnt(0)" ::: "memory");  // stores at coherent point
      __syncthreads();                                  // all waves drained
      if (tid == 0)                                     // publish (relaxed is enough)
        __hip_atomic_store(&flags[blk], (unsigned)(t + 1), __ATOMIC_RELAXED, __HIP_MEMORY_SCOPE_AGENT);
    }
  }
}

extern "C" void kernel_launch(void* const* d_in, const int* in_sizes, int n_in,
                              void* d_out, int out_size, void* d_ws, size_t ws_size,
                              hipStream_t stream) {
  const float* x   = (const float*)d_in[0];
  const float* Wg  = (const float*)d_in[1];
  const float* bg  = (const float*)d_in[2];
  const float* Wih = (const float*)d_in[3];
  const float* bih = (const float*)d_in[4];
  const float* Whh = (const float*)d_in[5];
  const float* bhh = (const float*)d_in[6];
  // d_in[7..10] (Wa, ba, Ws, bs) are mathematically dead: softmax over size-1 axis == 1
  float* out = (float*)d_out;

  char* ws = (char*)d_ws;
  _Float16* Wp    = (_Float16*)ws;                        // 5120*1536*2 = 15,728,640 B
  _Float16* Hbuf  = (_Float16*)(ws + 15728640);           // 2*64*1024*2 =   262,144 B
  unsigned* flags = (unsigned*)(ws + 15728640 + 262144);  // 256 B

  hipMemsetAsync((void*)Hbuf, 0, 262144 + 256, stream);   // h0 = 0, flags = 0
  prep_w<<<5120, 256, 0, stream>>>(Wg, Wih, Whh, Wp);
  rnn_seq<<<64, 512, 0, stream>>>(x, Wp, bg, bih, bhh, out, Hbuf, flags);
}

// Round 5
// 5281.344 us; speedup vs baseline: 1.3729x; 1.0212x over previous
//
#include <hip/hip_runtime.h>

typedef _Float16 half8 __attribute__((ext_vector_type(8)));
typedef float f32x4 __attribute__((ext_vector_type(4)));
typedef float f32x2 __attribute__((ext_vector_type(2)));

#define BB 64
#define SS 512
#define DD 512
#define HH 1024
#define KK 1536            // D + H
#define NBLK 64

// x-region of Wp: permute k within each 32-block so one contiguous 16B
// lane-load yields the mfma_16x16x32 fragment order. h-region: IDENTITY
// layout on both operands (permutation cancels inside the MFMA dot product).
__device__ __host__ __forceinline__ int kperm(int k) {
  int blk = k >> 5, r = k & 31;
  return (blk << 5) | (((r >> 2) & 3) << 3) | ((r >> 4) << 2) | (r & 3);
}

// Pack weights: Wp[p][k'] fp16, p = b*80 + tile*16 + c  (tile: 0=g,1=r,2=z,3=i_n,4=h_n)
__global__ void prep_w(const float* __restrict__ Wg, const float* __restrict__ Wih,
                       const float* __restrict__ Whh, _Float16* __restrict__ Wp) {
  int p = blockIdx.x;                       // 0..5119
  int b = p / 80, rem = p % 80, t = rem >> 4, c = rem & 15;
  int j = b * 16 + c;                       // h-column 0..1023
  for (int pass = 0; pass < 6; ++pass) {
    int k = pass * 256 + threadIdx.x;       // 0..1535
    float v;
    if (t == 0)      v = Wg[k * HH + j];
    else if (t == 1) v = (k < DD) ? Wih[k * 3 * HH + j]          : Whh[(k - DD) * 3 * HH + j];
    else if (t == 2) v = (k < DD) ? Wih[k * 3 * HH + HH + j]     : Whh[(k - DD) * 3 * HH + HH + j];
    else if (t == 3) v = (k < DD) ? Wih[k * 3 * HH + 2 * HH + j] : 0.f;
    else             v = (k < DD) ? 0.f : Whh[(k - DD) * 3 * HH + 2 * HH + j];
    int pos = (k < DD) ? kperm(k) : k;      // x: kperm'd, h: identity
    Wp[(size_t)p * KK + pos] = (_Float16)v;
  }
}

// Xh[t][sg][row][lkg][8]: fp16 x in MFMA-fragment-ready order.
// elems j<4 -> k = sg*32 + lkg*4 + j ; j>=4 -> k = sg*32 + 16 + lkg*4 + (j-4)
__global__ void prep_xh(const float* __restrict__ x, _Float16* __restrict__ Xh) {
  int t = blockIdx.x, sg = blockIdx.y;          // 512 x 16
  int row = threadIdx.x >> 2, lkg = threadIdx.x & 3;
  const float* xp = x + ((size_t)row * SS + t) * DD + sg * 32 + lkg * 4;
  half8 hv;
#pragma unroll
  for (int j = 0; j < 4; ++j) { hv[j] = (_Float16)xp[j]; hv[4 + j] = (_Float16)xp[16 + j]; }
  *(half8*)(Xh + ((((size_t)t * 16 + sg) * 64 + row) * 4 + lkg) * 8) = hv;
}

__global__ __launch_bounds__(512, 2) void rnn_seq(
    const _Float16* __restrict__ Xh, const _Float16* __restrict__ Wp,
    const float* __restrict__ bg, const float* __restrict__ bih,
    const float* __restrict__ bhh, float* __restrict__ out,
    _Float16* __restrict__ Hbuf, unsigned* __restrict__ flags) {
  const int blk = blockIdx.x;          // column block 0..63
  const int tid = threadIdx.x;
  const int w = tid >> 6;              // wave 0..7
  const int lane = tid & 63;
  const int lrow = lane & 15;
  const int lkg = lane >> 4;

  __shared__ float Red[4][80][68];               // 87,040 B
  __shared__ alignas(16) _Float16 Hst[64][16];   // 2,048 B
  __shared__ alignas(16) _Float16 Xstage[64 * 512];  // 65,536 B (64 chunks x 1KB)
  // total 154,624 B -> 1 block/CU

  const int ej = tid & 15;
  const int rpp = tid >> 4;            // 0..31
  const int ghcol = blk * 16 + ej;
  const float bg_b  = bg[ghcol];
  const float br_b  = bih[ghcol] + bhh[ghcol];
  const float bz_b  = bih[HH + ghcol] + bhh[HH + ghcol];
  const float bin_b = bih[2 * HH + ghcol];
  const float bhn_b = bhh[2 * HH + ghcol];
  float hreg[2] = {0.f, 0.f};

  // ---- prefetch Xh(t=0) into Xstage (wave-uniform LDS base + lane*16) ----
#pragma unroll
  for (int kk = 0; kk < 2; ++kk)
#pragma unroll
    for (int mt = 0; mt < 4; ++mt) {
      const _Float16* gsrc = Xh + ((((size_t)0 * 16 + (w * 2 + kk)) * 64 + (mt * 16 + lrow)) * 4 + lkg) * 8;
      __builtin_amdgcn_global_load_lds(
          (const __attribute__((address_space(1))) void*)gsrc,
          (__attribute__((address_space(3))) void*)(Xstage + (w * 8 + kk * 4 + mt) * 512),
          16, 0, 0);
    }

  // register-resident weights (24 half8 = 96 VGPR)
  half8 bx[3][2], b3[2], bh[3][4], b4[4];
#pragma unroll
  for (int tt = 0; tt < 3; ++tt)
#pragma unroll
    for (int kk = 0; kk < 2; ++kk)
      bx[tt][kk] = *(const half8*)(Wp + (size_t)(blk * 80 + tt * 16 + lrow) * KK + (w * 2 + kk) * 32 + lkg * 8);
#pragma unroll
  for (int kk = 0; kk < 2; ++kk)
    b3[kk] = *(const half8*)(Wp + (size_t)(blk * 80 + 48 + lrow) * KK + (w * 2 + kk) * 32 + lkg * 8);
#pragma unroll
  for (int tt = 0; tt < 3; ++tt)
#pragma unroll
    for (int kk = 0; kk < 4; ++kk)
      bh[tt][kk] = *(const half8*)(Wp + (size_t)(blk * 80 + tt * 16 + lrow) * KK + (16 + w * 4 + kk) * 32 + lkg * 8);
#pragma unroll
  for (int kk = 0; kk < 4; ++kk)
    b4[kk] = *(const half8*)(Wp + (size_t)(blk * 80 + 64 + lrow) * KK + (16 + w * 4 + kk) * 32 + lkg * 8);

  asm volatile("s_waitcnt vmcnt(0)" ::: "memory");   // Xstage(0) + weights resident
  __builtin_amdgcn_sched_barrier(0);

  for (int t = 0; t < SS; ++t) {
    const _Float16* Hb = Hbuf + (size_t)(t & 1) * (BB * HH);
    _Float16* Hn = Hbuf + (size_t)((t + 1) & 1) * (BB * HH);

    f32x4 zz = {0.f, 0.f, 0.f, 0.f};
    f32x4 acc[5][4];
#pragma unroll
    for (int tt = 0; tt < 5; ++tt)
#pragma unroll
      for (int mt = 0; mt < 4; ++mt) acc[tt][mt] = zz;

    // ---- x-part from LDS (prefetched last step) ----
#pragma unroll
    for (int kk = 0; kk < 2; ++kk) {
      half8 afr[4];
#pragma unroll
      for (int mt = 0; mt < 4; ++mt)
        afr[mt] = *(const half8*)(Xstage + (w * 8 + kk * 4 + mt) * 512 + lane * 8);
#pragma unroll
      for (int tt = 0; tt < 3; ++tt)
#pragma unroll
        for (int mt = 0; mt < 4; ++mt)
          acc[tt][mt] = __builtin_amdgcn_mfma_f32_16x16x32_f16(afr[mt], bx[tt][kk], acc[tt][mt], 0, 0, 0);
#pragma unroll
      for (int mt = 0; mt < 4; ++mt)
        acc[3][mt] = __builtin_amdgcn_mfma_f32_16x16x32_f16(afr[mt], b3[kk], acc[3][mt], 0, 0, 0);
    }

    // ---- wait for h(t) ----
    if (tid < NBLK) {
      for (;;) {
        unsigned v = __hip_atomic_load(&flags[tid], __ATOMIC_RELAXED, __HIP_MEMORY_SCOPE_AGENT);
        if (__all((int)(v >= (unsigned)t))) break;
        __builtin_amdgcn_s_sleep(1);
      }
    }
    __syncthreads();
    __builtin_amdgcn_sched_barrier(0);

    // ---- h-part: issue both sc1 batches, then Xh(t+1) prefetch; counted waits.
    // vmcnt retires in issue order: vmcnt(16) -> ha done; vmcnt(8) -> hb done.
    half8 ha[2][4], hb[2][4];
#pragma unroll
    for (int kk = 0; kk < 2; ++kk)
#pragma unroll
      for (int mt = 0; mt < 4; ++mt) {
        const _Float16* hp = Hb + (size_t)(mt * 16 + lrow) * HH + (w * 4 + kk) * 32 + lkg * 8;
        asm volatile("global_load_dwordx4 %0, %1, off sc0 sc1"
                     : "=v"(ha[kk][mt]) : "v"(hp) : "memory");
      }
#pragma unroll
    for (int kk = 0; kk < 2; ++kk)
#pragma unroll
      for (int mt = 0; mt < 4; ++mt) {
        const _Float16* hp = Hb + (size_t)(mt * 16 + lrow) * HH + (w * 4 + 2 + kk) * 32 + lkg * 8;
        asm volatile("global_load_dwordx4 %0, %1, off sc0 sc1"
                     : "=v"(hb[kk][mt]) : "v"(hp) : "memory");
      }
    if (t + 1 < SS) {
#pragma unroll
      for (int kk = 0; kk < 2; ++kk)
#pragma unroll
        for (int mt = 0; mt < 4; ++mt) {
          const _Float16* gsrc = Xh + ((((size_t)(t + 1) * 16 + (w * 2 + kk)) * 64 + (mt * 16 + lrow)) * 4 + lkg) * 8;
          __builtin_amdgcn_global_load_lds(
              (const __attribute__((address_space(1))) void*)gsrc,
              (__attribute__((address_space(3))) void*)(Xstage + (w * 8 + kk * 4 + mt) * 512),
              16, 0, 0);
        }
      asm volatile("s_waitcnt vmcnt(16)" ::: "memory");  // ha ready (hb+xpref in flight)
    } else {
      asm volatile("s_waitcnt vmcnt(8)" ::: "memory");   // ha ready (hb in flight)
    }
    __builtin_amdgcn_sched_barrier(0);
#pragma unroll
    for (int kk = 0; kk < 2; ++kk) {
#pragma unroll
      for (int tt = 0; tt < 3; ++tt)
#pragma unroll
        for (int mt = 0; mt < 4; ++mt)
          acc[tt][mt] = __builtin_amdgcn_mfma_f32_16x16x32_f16(ha[kk][mt], bh[tt][kk], acc[tt][mt], 0, 0, 0);
#pragma unroll
      for (int mt = 0; mt < 4; ++mt)
        acc[4][mt] = __builtin_amdgcn_mfma_f32_16x16x32_f16(ha[kk][mt], b4[kk], acc[4][mt], 0, 0, 0);
    }
    if (t + 1 < SS) asm volatile("s_waitcnt vmcnt(8)" ::: "memory");  // hb ready
    else            asm volatile("s_waitcnt vmcnt(0)" ::: "memory");
    __builtin_amdgcn_sched_barrier(0);
#pragma unroll
    for (int kk = 0; kk < 2; ++kk) {
#pragma unroll
      for (int tt = 0; tt < 3; ++tt)
#pragma unroll
        for (int mt = 0; mt < 4; ++mt)
          acc[tt][mt] = __builtin_amdgcn_mfma_f32_16x16x32_f16(hb[kk][mt], bh[tt][2 + kk], acc[tt][mt], 0, 0, 0);
#pragma unroll
      for (int mt = 0; mt < 4; ++mt)
        acc[4][mt] = __builtin_amdgcn_mfma_f32_16x16x32_f16(hb[kk][mt], b4[2 + kk], acc[4][mt], 0, 0, 0);
    }

    // ---- vectorized 2-phase cross-wave reduction (8 partials -> 4) ----
    if (w >= 4) {
#pragma unroll
      for (int tt = 0; tt < 5; ++tt)
#pragma unroll
        for (int mt = 0; mt < 4; ++mt)
          *(f32x4*)&Red[w - 4][tt * 16 + lrow][mt * 16 + lkg * 4] = acc[tt][mt];
    }
    __syncthreads();
    if (w < 4) {
#pragma unroll
      for (int tt = 0; tt < 5; ++tt)
#pragma unroll
        for (int mt = 0; mt < 4; ++mt) {
          f32x4* p = (f32x4*)&Red[w][tt * 16 + lrow][mt * 16 + lkg * 4];
          *p = *p + acc[tt][mt];
        }
    }
    __syncthreads();

    // ---- epilogue: all 512 threads, 2 rows x 1 col each ----
    {
      f32x2 s[5];
#pragma unroll
      for (int g = 0; g < 5; ++g) {
        f32x2 a = *(const f32x2*)&Red[0][g * 16 + ej][rpp * 2];
#pragma unroll
        for (int ww = 1; ww < 4; ++ww)
          a = a + *(const f32x2*)&Red[ww][g * 16 + ej][rpp * 2];
        s[g] = a;
      }
#pragma unroll
      for (int r = 0; r < 2; ++r) {
        float g_ = 1.f / (1.f + __expf(-(s[0][r] + bg_b)));
        float r_ = 1.f / (1.f + __expf(-(s[1][r] + br_b)));
        float z_ = 1.f / (1.f + __expf(-(s[2][r] + bz_b)));
        float n_ = tanhf(s[3][r] + bin_b + r_ * (s[4][r] + bhn_b));
        float h = g_ * ((1.f - z_) * n_ + z_ * hreg[r]);
        hreg[r] = h;
        int row = rpp * 2 + r;
        if (t == SS - 1) out[row * HH + ghcol] = h;
        else             Hst[row][ej] = (_Float16)h;
      }
    }

    if (t < SS - 1) {
      __syncthreads();                 // Hst complete
      if (tid < 128) {                 // 128 x 16B stores to the coherent point
        int row = tid >> 1, hf = tid & 1;
        half8 hv = *(const half8*)&Hst[row][hf * 8];
        _Float16* hp = Hn + (size_t)row * HH + blk * 16 + hf * 8;
        asm volatile("global_store_dwordx4 %0, %1, off sc0 sc1"
                     :: "v"(hp), "v"(hv) : "memory");
      }
      asm volatile("s_waitcnt vmcnt(0)" ::: "memory");  // stores drained (+ xpref done)
      __syncthreads();
      if (tid == 0)
        __hip_atomic_store(&flags[blk], (unsigned)(t + 1), __ATOMIC_RELAXED, __HIP_MEMORY_SCOPE_AGENT);
    }
  }
}

extern "C" void kernel_launch(void* const* d_in, const int* in_sizes, int n_in,
                              void* d_out, int out_size, void* d_ws, size_t ws_size,
                              hipStream_t stream) {
  const float* x   = (const float*)d_in[0];
  const float* Wg  = (const float*)d_in[1];
  const float* bg  = (const float*)d_in[2];
  const float* Wih = (const float*)d_in[3];
  const float* bih = (const float*)d_in[4];
  const float* Whh = (const float*)d_in[5];
  const float* bhh = (const float*)d_in[6];
  // d_in[7..10] (Wa, ba, Ws, bs) are mathematically dead: softmax over size-1 axis == 1
  float* out = (float*)d_out;

  char* ws = (char*)d_ws;
  _Float16* Wp    = (_Float16*)ws;                        // 15,728,640 B
  _Float16* Xh    = (_Float16*)(ws + 15728640);           // 512*16*64*4*8*2 = 33,554,432 B
  _Float16* Hbuf  = (_Float16*)(ws + 15728640 + 33554432);        // 262,144 B
  unsigned* flags = (unsigned*)(ws + 15728640 + 33554432 + 262144); // 256 B

  hipMemsetAsync((void*)Hbuf, 0, 262144 + 256, stream);   // h0 = 0, flags = 0
  prep_w<<<5120, 256, 0, stream>>>(Wg, Wih, Whh, Wp);
  prep_xh<<<dim3(512, 16), 256, 0, stream>>>(x, Xh);
  rnn_seq<<<64, 512, 0, stream>>>(Xh, Wp, bg, bih, bhh, out, Hbuf, flags);
}